// Round 10
// baseline (264.326 us; speedup 1.0000x reference)
//
#include <hip/hip_runtime.h>

// Fusedmax: out = sparsemax(prox_TV1D(x, alpha=1)) row-wise. B=4096, N=512, fp32.
//
// v10 (resubmit; prior round failed on container acquisition, not the kernel):
// v9 (bidirectional Condat, 2 waves/row, 8192 waves, VALUBusy 97% =
// pure issue-bound) with the two largest removable issue blocks cut, both
// bit-exact transforms of the verified v9 engine:
//  (a) FLOAT4 FLUSHES: segment flush loops write ds_write_b128 (constant
//      float4) on 16B-aligned interiors, scalar head/tail. ~70% fewer flush
//      instructions (~2k -> ~700 per row). In-place semantics unchanged
//      (flush writes <= frontier, reads ahead).
//  (b) CACHED TUBE BOUNDS vminl=vmin-lam / vmaxl=vmax+lam in the branchy
//      v3 control flow: -2 VALU per step, updated only at clamp fires and
//      segment resets. Identical values -> identical event sequence.
// At 97% busy every removed instruction is wall time; v4 proved the flush
// block is ~24% of scan issue (its deferral cut issue 24% but was neutral
// in the then latency-bound regime; its LDS cost would hurt occupancy here).
// Stop rule, staging, stitch, Michelot sparsemax: v9 verbatim.

#define TVN 512
#define LAMBDA 1.0f
#define STOPK 257

__device__ __forceinline__ float wave_reduce_sum(float v) {
#pragma unroll
    for (int off = 32; off > 0; off >>= 1) v += __shfl_xor(v, off, 64);
    return v;
}

// Flush row[i0..i1] = val with b128 interior (row must be 16B-aligned base).
#define FLUSH(I0, I1, VAL)                                              \
    {                                                                   \
        int _i = (I0);                                                  \
        const int _e = (I1);                                            \
        const float _v = (VAL);                                         \
        for (; _i <= _e && (_i & 3); ++_i) row[_i] = _v;                \
        const float4 _fv = make_float4(_v, _v, _v, _v);                 \
        for (; _i + 3 <= _e; _i += 4) *(float4*)&row[_i] = _fv;         \
        for (; _i <= _e; ++_i) row[_i] = _v;                            \
    }

// v9's verified lane-0 Condat scan + early stop, with cached tube bounds and
// float4 flushes. Event sequence bit-identical to v9/v3.
__device__ __forceinline__ void tv_scan_half(float* __restrict__ row) {
    const float lam = LAMBDA;
    const float yLast = row[TVN - 1];
    const float twolam = 2.0f * lam;
    int k = 0, k0 = 0, km = 0, kp = 0;
    float vmin = row[0] - lam, vmax = row[0] + lam;
    float vminl = vmin - lam, vmaxl = vmax + lam;   // cached tube bounds
    float umin = lam, umax = -lam;
    float cntf = 1.0f;                     // == (float)(k - k0 + 1)
    float yn;

#define ACCUM_STEP(W)                                                   \
    yn = (W);                                                           \
    if (yn + umin < vminl) goto neg_jump;                               \
    if (yn + umax > vmaxl) goto pos_jump;                               \
    ++k; cntf += 1.0f;                                                  \
    umin += yn - vmin;                                                  \
    umax += yn - vmax;                                                  \
    if (umin >= lam) {                                                  \
        vmin += (umin - lam) * __builtin_amdgcn_rcpf(cntf);             \
        vminl = vmin - lam;                                             \
        umin = lam; km = k;                                             \
    }                                                                   \
    if (umax <= -lam) {                                                 \
        vmax += (umax + lam) * __builtin_amdgcn_rcpf(cntf);             \
        vmaxl = vmax + lam;                                             \
        umax = -lam; kp = k;                                            \
    }                                                                   \
    if (k == TVN - 1) goto end_phase;

refill: {
        // k <= TVN-2 here: up to 8 accumulate steps from registers
        float w0 = row[k + 1], w1 = row[k + 2], w2 = row[k + 3], w3 = row[k + 4];
        float w4 = row[k + 5], w5 = row[k + 6], w6 = row[k + 7], w7 = row[k + 8];
        ACCUM_STEP(w0)
        ACCUM_STEP(w1)
        ACCUM_STEP(w2)
        ACCUM_STEP(w3)
        ACCUM_STEP(w4)
        ACCUM_STEP(w5)
        ACCUM_STEP(w6)
        ACCUM_STEP(w7)
        goto refill;
    }
#undef ACCUM_STEP

neg_jump: {
        FLUSH(k0, km, vmin);
        int nk = km + 1;                   // <= TVN-1, untouched index
        if (nk >= STOPK) return;           // coverage [0, nk-1] ⊇ [0, 256]: done
        float ynk = row[nk];
        k = k0 = km = kp = nk;
        vmin = ynk;
        vmax = ynk + twolam;
        vminl = vmin - lam; vmaxl = vmax + lam;
        umin = lam;
        umax = -lam;
        cntf = 1.0f;
        if (k == TVN - 1) goto end_phase;
        goto refill;
    }

pos_jump: {
        FLUSH(k0, kp, vmax);
        int nk = kp + 1;
        if (nk >= STOPK) return;           // coverage [0, nk-1] ⊇ [0, 256]: done
        float ynk = row[nk];
        k = k0 = km = kp = nk;
        vmax = ynk;
        vmin = ynk - twolam;
        vminl = vmin - lam; vmaxl = vmax + lam;
        umin = lam;
        umax = -lam;
        cntf = 1.0f;
        if (k == TVN - 1) goto end_phase;
        goto refill;
    }

end_phase: {
        // Reached only when no jump ever hit nk >= STOPK (giant tail segment):
        // run the verified full end phase to completion. No stop checks here
        // (rewind may rewrite earlier indices; completion is the safe path).
        for (;;) {
            if (umin < 0.0f) {             // end-phase negative jump
                FLUSH(k0, km, vmin);
                int nk = km + 1;
                float ynk = (nk > TVN - 1) ? yLast : row[nk];
                if (nk > TVN - 1) nk = TVN - 1;
                k = k0 = km = nk;
                vmin = ynk;
                vminl = vmin - lam;        // vmax/vmaxl unchanged (reference)
                umin = lam;
                umax = ynk + lam - vmax;   // old vmax
                cntf = 1.0f;
                if (k == TVN - 1) continue;
                goto refill;
            } else if (umax > 0.0f) {      // end-phase positive jump
                FLUSH(k0, kp, vmax);
                int nk = kp + 1;
                float ynk = (nk > TVN - 1) ? yLast : row[nk];
                if (nk > TVN - 1) nk = TVN - 1;
                k = k0 = kp = nk;
                vmax = ynk;
                vmaxl = vmax + lam;        // vmin/vminl unchanged (reference)
                umax = -lam;
                umin = ynk - lam - vmin;   // old vmin
                cntf = 1.0f;
                if (k == TVN - 1) continue;
                goto refill;
            } else {                       // finish
                float v = vmin + umin / (float)(k - k0 + 1);
                FLUSH(k0, TVN - 1, v);
                return;
            }
        }
    }
}

__global__ __launch_bounds__(128) void fusedmax_kernel(const float* __restrict__ xin,
                                                       float* __restrict__ out) {
    __shared__ alignas(16) float rowF[TVN + 8];   // forward buffer (+8 lookahead pad)
    __shared__ alignas(16) float rowR[TVN + 8];   // reversed buffer

    const int t = threadIdx.x;                 // 0..127
    const int w = t >> 6;                      // wave id: 0 = forward, 1 = backward
    const int lane = t & 63;
    const long long r = blockIdx.x;

    // ---- stage: wave 0 -> rowF coalesced; wave 1 -> rowR reversed ----
    const float4* __restrict__ g4 = (const float4*)(xin + r * TVN);
    if (w == 0) {
        float4* s4 = (float4*)rowF;
        s4[lane] = g4[lane];
        s4[lane + 64] = g4[lane + 64];
        if (lane < 8) rowF[TVN + lane] = 0.0f;
    } else {
        float4 a = g4[lane];                   // elems 4*lane .. 4*lane+3
        float4 b = g4[lane + 64];              // elems 256+4*lane ..
        const int ba = 511 - 4 * lane;
        rowR[ba] = a.x; rowR[ba - 1] = a.y; rowR[ba - 2] = a.z; rowR[ba - 3] = a.w;
        const int bb = 255 - 4 * lane;
        rowR[bb] = b.x; rowR[bb - 1] = b.y; rowR[bb - 2] = b.z; rowR[bb - 3] = b.w;
        if (lane < 8) rowR[TVN + lane] = 0.0f;
    }
    __syncthreads();

    // ---- two independent half-scans (lane 0 of each wave) ----
    if (lane == 0) tv_scan_half(w ? rowR : rowF);
    __syncthreads();

    // ---- stitched gather: i<=256 from rowF, i>=257 from rowR[511-i] ----
    float v[8];
#pragma unroll
    for (int j = 0; j < 4; ++j) v[j] = rowF[4 * lane + j];          // 0..255
    {
        const int i0 = 256 + 4 * lane;
        v[4] = (i0 == 256) ? rowF[256] : rowR[511 - i0];
        v[5] = rowR[511 - (i0 + 1)];
        v[6] = rowR[511 - (i0 + 2)];
        v[7] = rowR[511 - (i0 + 3)];
    }

    // ---- sparsemax via Michelot fixed point (exact tau, no sort) ----
    float ls = v[0] + v[1] + v[2] + v[3] + v[4] + v[5] + v[6] + v[7];
    float S = wave_reduce_sum(ls);
    float tau = (S - 1.0f) * (1.0f / (float)TVN);   // support = all
    int cprev = TVN;
#pragma unroll 1
    for (int it = 0; it < 64; ++it) {
        float s = 0.0f, c = 0.0f;
#pragma unroll
        for (int j = 0; j < 8; ++j) {
            if (v[j] > tau) { s += v[j]; c += 1.0f; }
        }
        s = wave_reduce_sum(s);
        c = wave_reduce_sum(c);               // >= 1 always (tau < max)
        tau = (s - 1.0f) / c;
        int ci = (int)c;
        if (ci == cprev) break;               // support stabilized -> tau exact
        cprev = ci;
    }

    // ---- each wave writes its half of the row ----
    float4 o;
    if (w == 0) {
        o.x = fmaxf(v[0] - tau, 0.0f);
        o.y = fmaxf(v[1] - tau, 0.0f);
        o.z = fmaxf(v[2] - tau, 0.0f);
        o.w = fmaxf(v[3] - tau, 0.0f);
    } else {
        o.x = fmaxf(v[4] - tau, 0.0f);
        o.y = fmaxf(v[5] - tau, 0.0f);
        o.z = fmaxf(v[6] - tau, 0.0f);
        o.w = fmaxf(v[7] - tau, 0.0f);
    }
    float4* __restrict__ o4 = (float4*)(out + r * TVN);
    o4[lane + ((w == 0) ? 0 : 64)] = o;
}

extern "C" void kernel_launch(void* const* d_in, const int* in_sizes, int n_in,
                              void* d_out, int out_size, void* d_ws, size_t ws_size,
                              hipStream_t stream) {
    const float* x = (const float*)d_in[0];
    float* out = (float*)d_out;
    const int rows = in_sizes[0] / TVN;       // 4096
    fusedmax_kernel<<<dim3(rows), dim3(128), 0, stream>>>(x, out);
}